// Round 6
// baseline (508.930 us; speedup 1.0000x reference)
//
#include <hip/hip_runtime.h>
#include <math.h>

#define V 128000
#define H 1024
#define NBLK 1024
#define NCHUNK 8000            // V / 16 rows per chunk
#define R_CACHED 48000

typedef float f32x4 __attribute__((ext_vector_type(4)));

// ws uint32 layout:
//   barrier A counters: u32[0 + i*16], i<8 (64B apart)   flag: u32[128]
//   barrier B counters: u32[192 + i*16]                  flag: u32[320]
//   partials:           f32[512 + 2*c], c < NCHUNK  (max, sumexp)
#define BARA_CNT 0
#define BARA_FLG 128
#define BARB_CNT 192
#define BARB_FLG 320
#define ZERO_N   384
#define PART_F   512

__global__ __launch_bounds__(384) void k_init(unsigned* __restrict__ wsu) {
    if (threadIdx.x < ZERO_N) wsu[threadIdx.x] = 0u;
}

__device__ __forceinline__ float wave_reduce_sum(float v) {
#pragma unroll
    for (int off = 32; off > 0; off >>= 1)
        v += __shfl_xor(v, off, 64);
    return v;
}

// Device-wide barrier: 8 spread arrival counters -> master sets flag.
// All 1024 blocks are co-resident (4 blocks/CU x 256 CUs), so spinning is safe.
__device__ __forceinline__ void grid_barrier(unsigned* cnt, unsigned* flg) {
    __syncthreads();
    if (threadIdx.x == 0) {
        __threadfence();   // make this block's prior writes device-visible
        __hip_atomic_fetch_add(cnt + (blockIdx.x & 7) * 16, 1u,
                               __ATOMIC_RELEASE, __HIP_MEMORY_SCOPE_AGENT);
        if (blockIdx.x == 0) {
            unsigned s;
            do {
                s = 0;
#pragma unroll
                for (int i = 0; i < 8; ++i)
                    s += __hip_atomic_load(cnt + i * 16, __ATOMIC_ACQUIRE,
                                           __HIP_MEMORY_SCOPE_AGENT);
                if (s < NBLK) __builtin_amdgcn_s_sleep(8);
            } while (s < NBLK);
            __hip_atomic_store(flg, 1u, __ATOMIC_RELEASE, __HIP_MEMORY_SCOPE_AGENT);
        } else {
            while (!__hip_atomic_load(flg, __ATOMIC_ACQUIRE, __HIP_MEMORY_SCOPE_AGENT))
                __builtin_amdgcn_s_sleep(16);
        }
        __threadfence();   // acquire side: invalidate stale cached lines
    }
    __syncthreads();
}

__global__ __launch_bounds__(256, 4) void k_all(
    const int* __restrict__ token_p, const float* __restrict__ hidden,
    const float* __restrict__ emb,
    const float* __restrict__ w_ih, const float* __restrict__ w_hh,
    const float* __restrict__ b_ih, const float* __restrict__ b_hh,
    const float* __restrict__ w_out, const float* __restrict__ b_out,
    float* __restrict__ d_out, float* __restrict__ ws_f)
{
    unsigned* wsu = (unsigned*)ws_f;
    __shared__ float g[6];
    __shared__ float sl[16];
    __shared__ float sm[256], ss[256];
    __shared__ float sC;

    const int wave = threadIdx.x >> 6;
    const int lane = threadIdx.x & 63;

    // ---------------- Phase 1: gates + combine. Block k owns hidden elem k.
    {
        const int k = blockIdx.x;
        const float* x = emb + (size_t)token_p[0] * H;  // low 32b ok (i32/i64 LE)

        const float* w_a; const float* v_a; int g_a; float bias_a;
        const float* w_b = nullptr; const float* v_b = nullptr; int g_b = 0; float bias_b = 0.f;
        if (wave == 0) {
            w_a = w_ih + (size_t)k * H;           v_a = x;      g_a = 0; bias_a = b_ih[k];
            w_b = w_hh + (size_t)k * H;           v_b = hidden; g_b = 3; bias_b = b_hh[k];
        } else if (wave == 1) {
            w_a = w_ih + (size_t)(H + k) * H;     v_a = x;      g_a = 1; bias_a = b_ih[H + k];
            w_b = w_hh + (size_t)(H + k) * H;     v_b = hidden; g_b = 4; bias_b = b_hh[H + k];
        } else if (wave == 2) {
            w_a = w_ih + (size_t)(2 * H + k) * H; v_a = x;      g_a = 2; bias_a = b_ih[2 * H + k];
        } else {
            w_a = w_hh + (size_t)(2 * H + k) * H; v_a = hidden; g_a = 5; bias_a = b_hh[2 * H + k];
        }

        const f32x4* wa4 = (const f32x4*)w_a; const f32x4* va4 = (const f32x4*)v_a;
        const f32x4* wb4 = (const f32x4*)w_b; const f32x4* vb4 = (const f32x4*)v_b;
        float a0 = 0.f, a1 = 0.f;
#pragma unroll
        for (int it = 0; it < 4; ++it) {
            f32x4 aw = wa4[it * 64 + lane];
            f32x4 av = va4[it * 64 + lane];
            a0 = fmaf(aw.x, av.x, a0); a0 = fmaf(aw.y, av.y, a0);
            a0 = fmaf(aw.z, av.z, a0); a0 = fmaf(aw.w, av.w, a0);
            if (wave < 2) {
                f32x4 bw = wb4[it * 64 + lane];
                f32x4 bv = vb4[it * 64 + lane];
                a1 = fmaf(bw.x, bv.x, a1); a1 = fmaf(bw.y, bv.y, a1);
                a1 = fmaf(bw.z, bv.z, a1); a1 = fmaf(bw.w, bv.w, a1);
            }
        }
        a0 = wave_reduce_sum(a0);
        if (wave < 2) a1 = wave_reduce_sum(a1);
        if (lane == 0) {
            g[g_a] = a0 + bias_a;
            if (wave < 2) g[g_b] = a1 + bias_b;
        }
        __syncthreads();
        if (threadIdx.x == 0) {
            const float r = 1.f / (1.f + expf(-(g[0] + g[3])));
            const float z = 1.f / (1.f + expf(-(g[1] + g[4])));
            const float n = tanhf(g[2] + r * g[5]);
            d_out[V + k] = (1.f - z) * n + z * hidden[k];
        }
    }

    grid_barrier(wsu + BARA_CNT, wsu + BARA_FLG);

    // ---------------- Phase 2: logits, grid-stride over 16-row chunks.
    {
        const f32x4* h4p = (const f32x4*)(d_out + V);
        f32x4 h4[4];
#pragma unroll
        for (int it = 0; it < 4; ++it) h4[it] = h4p[it * 64 + lane];

        for (int c = blockIdx.x; c < NCHUNK; c += NBLK) {
            const int base_row = c * 16 + wave * 4;
            float acc[4] = {0.f, 0.f, 0.f, 0.f};

            if (base_row + 3 < R_CACHED) {
#pragma unroll
                for (int i = 0; i < 4; ++i) {
                    const f32x4* w4 = (const f32x4*)(w_out + (size_t)(base_row + i) * H);
#pragma unroll
                    for (int it = 0; it < 4; ++it) {
                        f32x4 a = w4[it * 64 + lane];
                        acc[i] = fmaf(a.x, h4[it].x, acc[i]);
                        acc[i] = fmaf(a.y, h4[it].y, acc[i]);
                        acc[i] = fmaf(a.z, h4[it].z, acc[i]);
                        acc[i] = fmaf(a.w, h4[it].w, acc[i]);
                    }
                }
            } else {
#pragma unroll
                for (int i = 0; i < 4; ++i) {
                    const f32x4* w4 = (const f32x4*)(w_out + (size_t)(base_row + i) * H);
#pragma unroll
                    for (int it = 0; it < 4; ++it) {
                        f32x4 a = __builtin_nontemporal_load(w4 + it * 64 + lane);
                        acc[i] = fmaf(a.x, h4[it].x, acc[i]);
                        acc[i] = fmaf(a.y, h4[it].y, acc[i]);
                        acc[i] = fmaf(a.z, h4[it].z, acc[i]);
                        acc[i] = fmaf(a.w, h4[it].w, acc[i]);
                    }
                }
            }

#pragma unroll
            for (int i = 0; i < 4; ++i) {
                const float r = wave_reduce_sum(acc[i]);
                if (lane == 0) {
                    const float l = r + b_out[base_row + i];
                    d_out[base_row + i] = l;
                    sl[wave * 4 + i] = l;
                }
            }
            __syncthreads();
            if (threadIdx.x == 0) {
                float m = sl[0];
#pragma unroll
                for (int i = 1; i < 16; ++i) m = fmaxf(m, sl[i]);
                float s = 0.f;
#pragma unroll
                for (int i = 0; i < 16; ++i) s += expf(sl[i] - m);
                ws_f[PART_F + 2 * c]     = m;
                ws_f[PART_F + 2 * c + 1] = s;
            }
            __syncthreads();
        }
    }

    grid_barrier(wsu + BARB_CNT, wsu + BARB_FLG);

    // ---------------- Phase 3: redundant partial merge -> C; subtract.
    {
        const int t = threadIdx.x;
        float m = -INFINITY, s = 0.f;
        for (int j = t; j < NCHUNK; j += 256) {
            const float m2 = ws_f[PART_F + 2 * j];
            const float s2 = ws_f[PART_F + 2 * j + 1];
            if (m2 > m) { s = s * expf(m - m2) + s2; m = m2; }
            else        { s += s2 * expf(m2 - m); }
        }
        sm[t] = m; ss[t] = s;
        __syncthreads();
#pragma unroll
        for (int off = 128; off > 0; off >>= 1) {
            if (t < off) {
                const float m2 = sm[t + off], s2 = ss[t + off];
                float mm = sm[t], sc = ss[t];
                if (m2 > mm) { sc = sc * expf(mm - m2) + s2; mm = m2; }
                else         { sc += s2 * expf(m2 - mm); }
                sm[t] = mm; ss[t] = sc;
            }
            __syncthreads();
        }
        if (t == 0) sC = sm[0] + logf(ss[0]);
        __syncthreads();
        const float C = sC;

        const int idx = blockIdx.x * 256 + t;       // float4 index
        if (idx < V / 4) {
            f32x4* o4 = (f32x4*)d_out;
            f32x4 v = o4[idx];
            v.x -= C; v.y -= C; v.z -= C; v.w -= C;
            o4[idx] = v;
        }
    }
}

extern "C" void kernel_launch(void* const* d_in, const int* in_sizes, int n_in,
                              void* d_out_v, int out_size, void* d_ws, size_t ws_size,
                              hipStream_t stream) {
    const int*   token  = (const int*)d_in[0];
    const float* hidden = (const float*)d_in[1];
    const float* emb    = (const float*)d_in[2];
    const float* w_ih   = (const float*)d_in[3];
    const float* w_hh   = (const float*)d_in[4];
    const float* b_ih   = (const float*)d_in[5];
    const float* b_hh   = (const float*)d_in[6];
    const float* w_out  = (const float*)d_in[7];
    const float* b_out  = (const float*)d_in[8];
    float* d_out = (float*)d_out_v;
    float* ws    = (float*)d_ws;

    k_init<<<1, 384, 0, stream>>>((unsigned*)ws);
    k_all <<<NBLK, 256, 0, stream>>>(token, hidden, emb, w_ih, w_hh, b_ih, b_hh,
                                     w_out, b_out, d_out, ws);
}